// Round 8
// baseline (912.629 us; speedup 1.0000x reference)
//
#include <hip/hip_runtime.h>

#define D_DIM 1024
#define NROWS 8192

typedef float f32x4 __attribute__((ext_vector_type(4)));
typedef int   i32x4 __attribute__((ext_vector_type(4)));
typedef int   i32x8 __attribute__((ext_vector_type(8)));

typedef const __attribute__((address_space(1))) void* gaddr_t;
typedef __attribute__((address_space(3))) void* laddr_t;

__device__ __forceinline__ void load16_to_lds(const void* g, void* l) {
    __builtin_amdgcn_global_load_lds((gaddr_t)g, (laddr_t)l, 16, 0, 0);
}

// ---- kernel 1: fp32 row-normalize -> fp8 e4m3, one WAVE per row (no barriers).
// Plain linear K layout (the MX 16x16x128 lane wants stored-k [32fq,32fq+32),
// which is naturally two adjacent 16-B chunks — no K-permutation needed).
// Also zeroes the encoded-max array (ws is poisoned 0xAA each call).
__global__ __launch_bounds__(256) void normalize_rows(const float* __restrict__ ex,
                                                      const float* __restrict__ ey,
                                                      unsigned char* __restrict__ Aq,
                                                      unsigned char* __restrict__ Bq,
                                                      int* __restrict__ maxenc) {
    const int wave = threadIdx.x >> 6, lane = threadIdx.x & 63;
    const int r = blockIdx.x * 4 + wave;
    if (lane == 0) maxenc[r] = 0;   // 0 < int-encoding of any (cosine+2.0) > 0

    const float* src;
    unsigned char* dst;
    if (r < NROWS) { src = ex + (size_t)r * D_DIM;           dst = Aq + (size_t)r * D_DIM; }
    else           { src = ey + (size_t)(r - NROWS) * D_DIM; dst = Bq + (size_t)(r - NROWS) * D_DIM; }

    float4 v[4];
    float ss = 0.0f;
    #pragma unroll
    for (int j = 0; j < 4; ++j) {
        v[j] = ((const float4*)src)[lane + 64 * j];
        ss += v[j].x * v[j].x + v[j].y * v[j].y + v[j].z * v[j].z + v[j].w * v[j].w;
    }
    #pragma unroll
    for (int off = 32; off; off >>= 1) ss += __shfl_xor(ss, off, 64);
    float scale = 1.0f / fmaxf(sqrtf(ss), 1e-8f);

    #pragma unroll
    for (int j = 0; j < 4; ++j) {
        int pk = 0;   // v_cvt_pk_fp8_f32: RNE, saturating; |x| <= ~0.3, no overflow
        pk = __builtin_amdgcn_cvt_pk_fp8_f32(v[j].x * scale, v[j].y * scale, pk, false);
        pk = __builtin_amdgcn_cvt_pk_fp8_f32(v[j].z * scale, v[j].w * scale, pk, true);
        ((int*)dst)[lane + 64 * j] = pk;
    }
}

// ---- kernel 2: 128x128-tile MX-fp8 (16x16x128, unit scales) GEMM with fused
// row/col max. R8 vs R4/R5: the i32x8 MFMA operands are built with
// __builtin_shufflevector over two ds_read_b128 results — pure register-pair
// concatenation, no alloca (R5 spilled: FETCH 37MB->1.5GB), no per-element
// extracts (R4: VGPR 244, occupancy 11%). Frame is byte-identical to the proven
// R6 kernel: same staging map + 16-B XOR bank swizzle (chunk c of row r at pos
// c^(r&7)), same 2-barrier BK=128 K-loop, same epilogue. Fragment reads: lane
// (fq*16+fr) takes stored chunks 2fq,2fq+1 of its row at swizzled pos0, pos0^16
// — every 8-lane b128 phase covers all 8 chunks = all 32 banks (conflict-free).
__global__ __launch_bounds__(256, 3) void gemm_max(const unsigned char* __restrict__ A,
                                                   const unsigned char* __restrict__ B,
                                                   int* __restrict__ rowmax,
                                                   int* __restrict__ colmax) {
    __shared__ __align__(16) unsigned char Alds[128 * 128];   // 16 KB
    __shared__ __align__(16) unsigned char Blds[128 * 128];   // 16 KB

    const int bm = blockIdx.x >> 6;
    const int bn = blockIdx.x & 63;
    const int rowb = bm * 128;
    const int colb = bn * 128;

    const int t    = threadIdx.x;
    const int lane = t & 63;
    const int wave = t >> 6;
    const int wm = (wave & 1) * 64;       // wave row offset within tile
    const int wn = (wave >> 1) * 64;      // wave col offset within tile
    const int fr = lane & 15;             // fragment row/col index
    const int fq = lane >> 4;             // k-block index: stored k = fq*32 .. fq*32+31
    const int pos0 = ((fq << 1) ^ (fr & 7)) * 16;   // swizzled pos of chunk 2fq
    const int pos1 = pos0 ^ 16;                     // chunk 2fq+1

    // staging: thread t stages LDS (row t>>3, pos t&7) <- global chunk (t&7)^(row&7)
    const int srow = t >> 3;
    const int scol = ((t ^ (t >> 3)) & 7) * 16;

    const unsigned char* Ag = A + (size_t)(rowb + srow) * D_DIM + scol;
    const unsigned char* Bg = B + (size_t)(colb + srow) * D_DIM + scol;

    f32x4 acc[4][4] = {};
    const int SC = 0x7F7F7F7F;   // E8M0 = 127 (scale 1.0) in every byte -> opsel moot

    for (int kt = 0; kt < D_DIM; kt += 128) {
        #pragma unroll
        for (int i = 0; i < 4; ++i)
            load16_to_lds(Ag + (size_t)i * 32 * D_DIM + kt,
                          (char*)Alds + i * 4096 + wave * 1024);
        #pragma unroll
        for (int i = 0; i < 4; ++i)
            load16_to_lds(Bg + (size_t)i * 32 * D_DIM + kt,
                          (char*)Blds + i * 4096 + wave * 1024);
        __syncthreads();

        i32x8 av[4];
        #pragma unroll
        for (int i = 0; i < 4; ++i) {
            const unsigned char* p = Alds + (wm + i * 16 + fr) * 128;
            i32x4 lo = *(const i32x4*)(p + pos0);
            i32x4 hi = *(const i32x4*)(p + pos1);
            av[i] = __builtin_shufflevector(lo, hi, 0, 1, 2, 3, 4, 5, 6, 7);
        }
        #pragma unroll
        for (int j = 0; j < 4; ++j) {
            const unsigned char* p = Blds + (wn + j * 16 + fr) * 128;
            i32x4 lo = *(const i32x4*)(p + pos0);
            i32x4 hi = *(const i32x4*)(p + pos1);
            i32x8 bv = __builtin_shufflevector(lo, hi, 0, 1, 2, 3, 4, 5, 6, 7);
            #pragma unroll
            for (int i = 0; i < 4; ++i)
                acc[i][j] = __builtin_amdgcn_mfma_scale_f32_16x16x128_f8f6f4(
                    av[i], bv, acc[i][j], 0 /*fp8 A*/, 0 /*fp8 B*/, 0, SC, 0, SC);
        }
        __syncthreads();
    }

    // ---- epilogue: fused max reductions.
    // C/D layout (shape-determined, m89/m121/m127): col = lane&15, row = fq*4 + reg.
    const float SH = 2.0f;   // cosine >= -1 -> v+2 > 0 -> int-ordered float bits

    #pragma unroll
    for (int i = 0; i < 4; ++i) {
        #pragma unroll
        for (int r = 0; r < 4; ++r) {
            float m = fmaxf(fmaxf(acc[i][0][r], acc[i][1][r]),
                            fmaxf(acc[i][2][r], acc[i][3][r]));
            m = fmaxf(m, __shfl_xor(m, 1, 64));   // reduce over the 16 lanes sharing fq
            m = fmaxf(m, __shfl_xor(m, 2, 64));
            m = fmaxf(m, __shfl_xor(m, 4, 64));
            m = fmaxf(m, __shfl_xor(m, 8, 64));
            if (fr == 0) {
                int row = rowb + wm + i * 16 + fq * 4 + r;
                atomicMax(&rowmax[row], __float_as_int(m + SH));
            }
        }
    }
    #pragma unroll
    for (int j = 0; j < 4; ++j) {
        float m = -1e30f;
        #pragma unroll
        for (int i = 0; i < 4; ++i)
            #pragma unroll
            for (int r = 0; r < 4; ++r)
                m = fmaxf(m, acc[i][j][r]);
        m = fmaxf(m, __shfl_xor(m, 16, 64));      // reduce over the 4 quarters
        m = fmaxf(m, __shfl_xor(m, 32, 64));
        if (fq == 0) {
            int col = colb + wn + j * 16 + fr;
            atomicMax(&colmax[col], __float_as_int(m + SH));
        }
    }
}

// ---- kernel 3: decode maxes, log-prob, sum. block 0 -> C1 (rowmax), block 1 -> C2 (colmax)
__global__ __launch_bounds__(256) void finalize(const int* __restrict__ rowmax,
                                                const int* __restrict__ colmax,
                                                float* __restrict__ out) {
    const int* src = (blockIdx.x == 0) ? rowmax : colmax;
    int t = threadIdx.x;
    float s = 0.0f;
    for (int i = t; i < NROWS; i += 256) {
        float v = __int_as_float(src[i]) - 2.0f;
        float z = (v - 1.0f) * (1.0f / 0.3f);
        s += -0.5f * z * z + 0.2850342711212634f;   // -(log(0.3)+0.5*log(2*pi))
    }
    #pragma unroll
    for (int off = 32; off; off >>= 1) s += __shfl_xor(s, off, 64);
    __shared__ float wsum[4];
    if ((t & 63) == 0) wsum[t >> 6] = s;
    __syncthreads();
    if (t == 0) out[blockIdx.x] = wsum[0] + wsum[1] + wsum[2] + wsum[3];
}

extern "C" void kernel_launch(void* const* d_in, const int* in_sizes, int n_in,
                              void* d_out, int out_size, void* d_ws, size_t ws_size,
                              hipStream_t stream) {
    const float* ex = (const float*)d_in[0];
    const float* ey = (const float*)d_in[1];
    float* out = (float*)d_out;

    char* ws = (char*)d_ws;
    unsigned char* Aq = (unsigned char*)ws;                                   // 8 MB
    unsigned char* Bq = (unsigned char*)(ws + (size_t)NROWS * D_DIM);         // 8 MB
    int* rowmax = (int*)(ws + (size_t)2 * NROWS * D_DIM);                     // 32 KB
    int* colmax = rowmax + NROWS;                                             // 32 KB

    normalize_rows<<<(2 * NROWS) / 4, 256, 0, stream>>>(ex, ey, Aq, Bq, rowmax);
    gemm_max<<<64 * 64, 256, 0, stream>>>(Aq, Bq, rowmax, colmax);
    finalize<<<2, 256, 0, stream>>>(rowmax, colmax, out);
}

// Round 9
// 196.240 us; speedup vs baseline: 4.6506x; 4.6506x over previous
//
#include <hip/hip_runtime.h>

#define D_DIM 1024
#define NROWS 8192

typedef float f32x4 __attribute__((ext_vector_type(4)));
typedef long  i64x2 __attribute__((ext_vector_type(2)));

typedef const __attribute__((address_space(1))) void* gaddr_t;
typedef __attribute__((address_space(3))) void* laddr_t;

__device__ __forceinline__ void load16_to_lds(const void* g, void* l) {
    __builtin_amdgcn_global_load_lds((gaddr_t)g, (laddr_t)l, 16, 0, 0);
}

// ---- kernel 1: fp32 row-normalize -> fp8 e4m3, one WAVE per row (no barriers).
// K is PERMUTED within each 128-element block (identically for A and B — dot
// products are K-permutation-invariant) so that the GEMM's two 8-B fragments
// for MFMA steps (0,1) and (2,3) are 16-B-contiguous: orig k = 32s+8f+b
// (s=step 0..3, f=lane quarter 0..3, b=0..7) is stored at byte
// (f + 4*(s>>1))*16 + (s&1)*8 + b of the block. Writes stay within their
// 128-B line -> fully coalesced. Also zeroes the encoded-max array (ws is
// poisoned 0xAA each call).
__global__ __launch_bounds__(256) void normalize_rows(const float* __restrict__ ex,
                                                      const float* __restrict__ ey,
                                                      unsigned char* __restrict__ Aq,
                                                      unsigned char* __restrict__ Bq,
                                                      int* __restrict__ maxenc) {
    const int wave = threadIdx.x >> 6, lane = threadIdx.x & 63;
    const int r = blockIdx.x * 4 + wave;
    if (lane == 0) maxenc[r] = 0;   // 0 < int-encoding of any (cosine+2.0) > 0

    const float* src;
    unsigned char* dst;
    if (r < NROWS) { src = ex + (size_t)r * D_DIM;           dst = Aq + (size_t)r * D_DIM; }
    else           { src = ey + (size_t)(r - NROWS) * D_DIM; dst = Bq + (size_t)(r - NROWS) * D_DIM; }

    float4 v[4];
    float ss = 0.0f;
    #pragma unroll
    for (int j = 0; j < 4; ++j) {
        v[j] = ((const float4*)src)[lane + 64 * j];
        ss += v[j].x * v[j].x + v[j].y * v[j].y + v[j].z * v[j].z + v[j].w * v[j].w;
    }
    #pragma unroll
    for (int off = 32; off; off >>= 1) ss += __shfl_xor(ss, off, 64);
    float scale = 1.0f / fmaxf(sqrtf(ss), 1e-8f);

    #pragma unroll
    for (int j = 0; j < 4; ++j) {
        int p = (lane + 64 * j) << 2;          // orig byte index of this 4-pack
        int blk = p >> 7, w = p & 127;
        int s = w >> 5, f = (w >> 3) & 3, b = w & 7;
        int q = blk * 128 + (f + ((s >> 1) << 2)) * 16 + (s & 1) * 8 + b;
        int pk = 0;   // v_cvt_pk_fp8_f32: RNE, saturating; |x| <= ~0.3, no overflow
        pk = __builtin_amdgcn_cvt_pk_fp8_f32(v[j].x * scale, v[j].y * scale, pk, false);
        pk = __builtin_amdgcn_cvt_pk_fp8_f32(v[j].z * scale, v[j].w * scale, pk, true);
        ((int*)dst)[q >> 2] = pk;
    }
}

// ---- kernel 2: 128x128-tile fp8 MFMA GEMM (C = A . B^T) with fused row/col max.
// Exact R6 structure (BK=128, 2-barrier, 32 KB LDS, mfma_f32_16x16x32_fp8_fp8,
// VGPR 84, zero bank conflicts via 16-B XOR swizzle + K-permutation -> paired
// ds_read_b128). R9 adds an XCD-aware 8x8 supertile block swizzle:
// bid = (s<<6)|(p<<3)|x  ->  bm = ((s&7)<<3)|p, bn = ((s>>3)<<3)|x.
// Every 64 consecutive bids form an 8x8 (bm,bn) supertile (2 MB working set);
// with round-robin bid->XCD, XCD x gets a fixed bn stripe (~1.1 MB < 4 MB L2),
// so staging reads hit per-XCD L2 (~200 cyc) instead of LLC — the single-
// buffered K-loop's pre-barrier vmcnt(0) drain sits on exactly that latency.
__global__ __launch_bounds__(256) void gemm_max(const unsigned char* __restrict__ A,
                                                const unsigned char* __restrict__ B,
                                                int* __restrict__ rowmax,
                                                int* __restrict__ colmax) {
    __shared__ __align__(16) unsigned char Alds[128 * 128];   // 16 KB
    __shared__ __align__(16) unsigned char Blds[128 * 128];   // 16 KB

    const int bid = blockIdx.x;
    const int sgr = bid >> 6;
    const int bm  = ((sgr & 7) << 3) | ((bid >> 3) & 7);
    const int bn  = ((sgr >> 3) << 3) | (bid & 7);
    const int rowb = bm * 128;
    const int colb = bn * 128;

    const int t    = threadIdx.x;
    const int lane = t & 63;
    const int wave = t >> 6;
    const int wm = (wave & 1) * 64;       // wave row offset within tile
    const int wn = (wave >> 1) * 64;      // wave col offset within tile
    const int fr = lane & 15;             // fragment row/col index
    const int fq = lane >> 4;             // quarter: frag k-bytes 8*fq in each step
    const int pos1 = (fq ^ (fr & 7)) * 16;   // swizzled pos of chunk fq  (steps 0,1)
    const int pos2 = pos1 ^ 64;              // chunk fq+4 (steps 2,3): bit2 flip

    // staging: thread t stages LDS (row t>>3, pos t&7) <- global chunk (t&7)^(row&7)
    const int srow = t >> 3;
    const int scol = ((t ^ (t >> 3)) & 7) * 16;

    const unsigned char* Ag = A + (size_t)(rowb + srow) * D_DIM + scol;
    const unsigned char* Bg = B + (size_t)(colb + srow) * D_DIM + scol;

    f32x4 acc[4][4] = {};

    for (int kt = 0; kt < D_DIM; kt += 128) {
        #pragma unroll
        for (int i = 0; i < 4; ++i)
            load16_to_lds(Ag + (size_t)i * 32 * D_DIM + kt,
                          (char*)Alds + i * 4096 + wave * 1024);
        #pragma unroll
        for (int i = 0; i < 4; ++i)
            load16_to_lds(Bg + (size_t)i * 32 * D_DIM + kt,
                          (char*)Blds + i * 4096 + wave * 1024);
        __syncthreads();

        i64x2 a1[4], a2[4];
        #pragma unroll
        for (int i = 0; i < 4; ++i) {
            const unsigned char* p = Alds + (wm + i * 16 + fr) * 128;
            a1[i] = *(const i64x2*)(p + pos1);   // ds_read_b128: steps 0,1
            a2[i] = *(const i64x2*)(p + pos2);   // ds_read_b128: steps 2,3
        }
        #pragma unroll
        for (int j = 0; j < 4; ++j) {
            const unsigned char* p = Blds + (wn + j * 16 + fr) * 128;
            i64x2 b1 = *(const i64x2*)(p + pos1);
            i64x2 b2 = *(const i64x2*)(p + pos2);
            #pragma unroll
            for (int i = 0; i < 4; ++i) {
                acc[i][j] = __builtin_amdgcn_mfma_f32_16x16x32_fp8_fp8(a1[i][0], b1[0], acc[i][j], 0, 0, 0);
                acc[i][j] = __builtin_amdgcn_mfma_f32_16x16x32_fp8_fp8(a1[i][1], b1[1], acc[i][j], 0, 0, 0);
                acc[i][j] = __builtin_amdgcn_mfma_f32_16x16x32_fp8_fp8(a2[i][0], b2[0], acc[i][j], 0, 0, 0);
                acc[i][j] = __builtin_amdgcn_mfma_f32_16x16x32_fp8_fp8(a2[i][1], b2[1], acc[i][j], 0, 0, 0);
            }
        }
        __syncthreads();
    }

    // ---- epilogue: fused max reductions.
    // C/D layout (shape-determined, m89-verified): col = lane&15, row = fq*4 + reg.
    const float SH = 2.0f;   // cosine >= -1 -> v+2 > 0 -> int-ordered float bits

    #pragma unroll
    for (int i = 0; i < 4; ++i) {
        #pragma unroll
        for (int r = 0; r < 4; ++r) {
            float m = fmaxf(fmaxf(acc[i][0][r], acc[i][1][r]),
                            fmaxf(acc[i][2][r], acc[i][3][r]));
            m = fmaxf(m, __shfl_xor(m, 1, 64));   // reduce over the 16 lanes sharing fq
            m = fmaxf(m, __shfl_xor(m, 2, 64));
            m = fmaxf(m, __shfl_xor(m, 4, 64));
            m = fmaxf(m, __shfl_xor(m, 8, 64));
            if (fr == 0) {
                int row = rowb + wm + i * 16 + fq * 4 + r;
                atomicMax(&rowmax[row], __float_as_int(m + SH));
            }
        }
    }
    #pragma unroll
    for (int j = 0; j < 4; ++j) {
        float m = -1e30f;
        #pragma unroll
        for (int i = 0; i < 4; ++i)
            #pragma unroll
            for (int r = 0; r < 4; ++r)
                m = fmaxf(m, acc[i][j][r]);
        m = fmaxf(m, __shfl_xor(m, 16, 64));      // reduce over the 4 quarters
        m = fmaxf(m, __shfl_xor(m, 32, 64));
        if (fq == 0) {
            int col = colb + wn + j * 16 + fr;
            atomicMax(&colmax[col], __float_as_int(m + SH));
        }
    }
}

// ---- kernel 3: decode maxes, log-prob, sum. block 0 -> C1 (rowmax), block 1 -> C2 (colmax)
__global__ __launch_bounds__(256) void finalize(const int* __restrict__ rowmax,
                                                const int* __restrict__ colmax,
                                                float* __restrict__ out) {
    const int* src = (blockIdx.x == 0) ? rowmax : colmax;
    int t = threadIdx.x;
    float s = 0.0f;
    for (int i = t; i < NROWS; i += 256) {
        float v = __int_as_float(src[i]) - 2.0f;
        float z = (v - 1.0f) * (1.0f / 0.3f);
        s += -0.5f * z * z + 0.2850342711212634f;   // -(log(0.3)+0.5*log(2*pi))
    }
    #pragma unroll
    for (int off = 32; off; off >>= 1) s += __shfl_xor(s, off, 64);
    __shared__ float wsum[4];
    if ((t & 63) == 0) wsum[t >> 6] = s;
    __syncthreads();
    if (t == 0) out[blockIdx.x] = wsum[0] + wsum[1] + wsum[2] + wsum[3];
}

extern "C" void kernel_launch(void* const* d_in, const int* in_sizes, int n_in,
                              void* d_out, int out_size, void* d_ws, size_t ws_size,
                              hipStream_t stream) {
    const float* ex = (const float*)d_in[0];
    const float* ey = (const float*)d_in[1];
    float* out = (float*)d_out;

    char* ws = (char*)d_ws;
    unsigned char* Aq = (unsigned char*)ws;                                   // 8 MB
    unsigned char* Bq = (unsigned char*)(ws + (size_t)NROWS * D_DIM);         // 8 MB
    int* rowmax = (int*)(ws + (size_t)2 * NROWS * D_DIM);                     // 32 KB
    int* colmax = rowmax + NROWS;                                             // 32 KB

    normalize_rows<<<(2 * NROWS) / 4, 256, 0, stream>>>(ex, ey, Aq, Bq, rowmax);
    gemm_max<<<64 * 64, 256, 0, stream>>>(Aq, Bq, rowmax, colmax);
    finalize<<<2, 256, 0, stream>>>(rowmax, colmax, out);
}

// Round 10
// 179.774 us; speedup vs baseline: 5.0765x; 1.0916x over previous
//
#include <hip/hip_runtime.h>

#define D_DIM 1024
#define NROWS 8192

typedef float f32x4 __attribute__((ext_vector_type(4)));
typedef long  i64x2 __attribute__((ext_vector_type(2)));

typedef const __attribute__((address_space(1))) void* gaddr_t;
typedef __attribute__((address_space(3))) void* laddr_t;

__device__ __forceinline__ void load16_to_lds(const void* g, void* l) {
    __builtin_amdgcn_global_load_lds((gaddr_t)g, (laddr_t)l, 16, 0, 0);
}

// ---- kernel 1: fp32 row-normalize -> fp8 e4m3, one WAVE per row (no barriers).
// K is PERMUTED within each 128-element block (identically for A and B — dot
// products are K-permutation-invariant): orig k = 32s+8f+b (s=step 0..3,
// f=lane quarter 0..3, b=0..7) stored at byte (f + 4*(s>>1))*16 + (s&1)*8 + b.
// Writes stay within their 128-B line -> coalesced. Also zeroes the
// encoded-max array and d_out (both poisoned 0xAA before every launch).
__global__ __launch_bounds__(256) void normalize_rows(const float* __restrict__ ex,
                                                      const float* __restrict__ ey,
                                                      unsigned char* __restrict__ Aq,
                                                      unsigned char* __restrict__ Bq,
                                                      int* __restrict__ maxenc,
                                                      float* __restrict__ out) {
    const int wave = threadIdx.x >> 6, lane = threadIdx.x & 63;
    const int r = blockIdx.x * 4 + wave;
    if (lane == 0) maxenc[r] = 0;   // 0 < int-encoding of any (cosine+2.0) > 0
    if (blockIdx.x == 0 && threadIdx.x < 2) out[threadIdx.x] = 0.0f;

    const float* src;
    unsigned char* dst;
    if (r < NROWS) { src = ex + (size_t)r * D_DIM;           dst = Aq + (size_t)r * D_DIM; }
    else           { src = ey + (size_t)(r - NROWS) * D_DIM; dst = Bq + (size_t)(r - NROWS) * D_DIM; }

    float4 v[4];
    float ss = 0.0f;
    #pragma unroll
    for (int j = 0; j < 4; ++j) {
        v[j] = ((const float4*)src)[lane + 64 * j];
        ss += v[j].x * v[j].x + v[j].y * v[j].y + v[j].z * v[j].z + v[j].w * v[j].w;
    }
    #pragma unroll
    for (int off = 32; off; off >>= 1) ss += __shfl_xor(ss, off, 64);
    float scale = 1.0f / fmaxf(sqrtf(ss), 1e-8f);

    #pragma unroll
    for (int j = 0; j < 4; ++j) {
        int p = (lane + 64 * j) << 2;          // orig byte index of this 4-pack
        int blk = p >> 7, w = p & 127;
        int s = w >> 5, f = (w >> 3) & 3, b = w & 7;
        int q = blk * 128 + (f + ((s >> 1) << 2)) * 16 + (s & 1) * 8 + b;
        int pk = 0;   // v_cvt_pk_fp8_f32: RNE, saturating; |x| <= ~0.3, no overflow
        pk = __builtin_amdgcn_cvt_pk_fp8_f32(v[j].x * scale, v[j].y * scale, pk, false);
        pk = __builtin_amdgcn_cvt_pk_fp8_f32(v[j].z * scale, v[j].w * scale, pk, true);
        ((int*)dst)[q >> 2] = pk;
    }
}

// ---- kernel 2: 128x128-tile fp8 MFMA GEMM (C = A . B^T) with fused row/col max.
// R6/R9 frame: BK=128, 2-barrier K-loop, 32 KB LDS, mfma_f32_16x16x32_fp8_fp8,
// zero bank conflicts (16-B XOR swizzle + K-permutation -> paired ds_read_b128),
// XCD-aware 8x8 supertile block swizzle (R9: 122->103 us).
// R10: occupancy was register-bound at 80 VGPR + 64 AGPR = 144 combined
// (3 waves/SIMD on the unified gfx950 file). The kt body is split into two
// half-K passes (h=0: chunks pos1 = MFMA steps 0,1; h=1: pos2 = steps 2,3) so
// only 4 A-fragments (16 VGPRs) are live at a time instead of 8 (32).
// __launch_bounds__(256,4) pins the combined budget to 128 -> 4 waves/SIMD.
__global__ __launch_bounds__(256, 4) void gemm_max(const unsigned char* __restrict__ A,
                                                   const unsigned char* __restrict__ B,
                                                   int* __restrict__ rowmax,
                                                   int* __restrict__ colmax) {
    __shared__ __align__(16) unsigned char Alds[128 * 128];   // 16 KB
    __shared__ __align__(16) unsigned char Blds[128 * 128];   // 16 KB

    const int bid = blockIdx.x;
    const int sgr = bid >> 6;
    const int bm  = ((sgr & 7) << 3) | ((bid >> 3) & 7);
    const int bn  = ((sgr >> 3) << 3) | (bid & 7);
    const int rowb = bm * 128;
    const int colb = bn * 128;

    const int t    = threadIdx.x;
    const int lane = t & 63;
    const int wave = t >> 6;
    const int wm = (wave & 1) * 64;       // wave row offset within tile
    const int wn = (wave >> 1) * 64;      // wave col offset within tile
    const int fr = lane & 15;             // fragment row/col index
    const int fq = lane >> 4;             // quarter: frag k-bytes 8*fq in each step
    const int pos1 = (fq ^ (fr & 7)) * 16;   // swizzled pos of chunk fq  (steps 0,1)

    // staging: thread t stages LDS (row t>>3, pos t&7) <- global chunk (t&7)^(row&7)
    const int srow = t >> 3;
    const int scol = ((t ^ (t >> 3)) & 7) * 16;

    const unsigned char* Ag = A + (size_t)(rowb + srow) * D_DIM + scol;
    const unsigned char* Bg = B + (size_t)(colb + srow) * D_DIM + scol;

    f32x4 acc[4][4] = {};

    for (int kt = 0; kt < D_DIM; kt += 128) {
        #pragma unroll
        for (int i = 0; i < 4; ++i)
            load16_to_lds(Ag + (size_t)i * 32 * D_DIM + kt,
                          (char*)Alds + i * 4096 + wave * 1024);
        #pragma unroll
        for (int i = 0; i < 4; ++i)
            load16_to_lds(Bg + (size_t)i * 32 * D_DIM + kt,
                          (char*)Blds + i * 4096 + wave * 1024);
        __syncthreads();

        #pragma unroll
        for (int h = 0; h < 2; ++h) {
            const int pos = pos1 ^ (h << 6);   // h=0: chunk fq (steps 0,1); h=1: chunk fq+4 (steps 2,3)
            i64x2 af[4];
            #pragma unroll
            for (int i = 0; i < 4; ++i)
                af[i] = *(const i64x2*)(Alds + (wm + i * 16 + fr) * 128 + pos);
            #pragma unroll
            for (int j = 0; j < 4; ++j) {
                i64x2 bf = *(const i64x2*)(Blds + (wn + j * 16 + fr) * 128 + pos);
                #pragma unroll
                for (int i = 0; i < 4; ++i) {
                    acc[i][j] = __builtin_amdgcn_mfma_f32_16x16x32_fp8_fp8(af[i][0], bf[0], acc[i][j], 0, 0, 0);
                    acc[i][j] = __builtin_amdgcn_mfma_f32_16x16x32_fp8_fp8(af[i][1], bf[1], acc[i][j], 0, 0, 0);
                }
            }
        }
        __syncthreads();
    }

    // ---- epilogue: fused max reductions.
    // C/D layout (shape-determined, m89-verified): col = lane&15, row = fq*4 + reg.
    const float SH = 2.0f;   // cosine >= -1 -> v+2 > 0 -> int-ordered float bits

    #pragma unroll
    for (int i = 0; i < 4; ++i) {
        #pragma unroll
        for (int r = 0; r < 4; ++r) {
            float m = fmaxf(fmaxf(acc[i][0][r], acc[i][1][r]),
                            fmaxf(acc[i][2][r], acc[i][3][r]));
            m = fmaxf(m, __shfl_xor(m, 1, 64));   // reduce over the 16 lanes sharing fq
            m = fmaxf(m, __shfl_xor(m, 2, 64));
            m = fmaxf(m, __shfl_xor(m, 4, 64));
            m = fmaxf(m, __shfl_xor(m, 8, 64));
            if (fr == 0) {
                int row = rowb + wm + i * 16 + fq * 4 + r;
                atomicMax(&rowmax[row], __float_as_int(m + SH));
            }
        }
    }
    #pragma unroll
    for (int j = 0; j < 4; ++j) {
        float m = -1e30f;
        #pragma unroll
        for (int i = 0; i < 4; ++i)
            #pragma unroll
            for (int r = 0; r < 4; ++r)
                m = fmaxf(m, acc[i][j][r]);
        m = fmaxf(m, __shfl_xor(m, 16, 64));      // reduce over the 4 quarters
        m = fmaxf(m, __shfl_xor(m, 32, 64));
        if (fq == 0) {
            int col = colb + wn + j * 16 + fr;
            atomicMax(&colmax[col], __float_as_int(m + SH));
        }
    }
}

// ---- kernel 3: decode maxes, log-prob, partial-sum, atomicAdd into out.
// 64 blocks x 256 threads over the contiguous [rowmax | colmax] array; each
// block's 256 entries lie entirely in one half. out zeroed by normalize_rows.
__global__ __launch_bounds__(256) void finalize(const int* __restrict__ maxenc,
                                                float* __restrict__ out) {
    int idx = blockIdx.x * 256 + threadIdx.x;
    float v = __int_as_float(maxenc[idx]) - 2.0f;
    float z = (v - 1.0f) * (1.0f / 0.3f);
    float s = -0.5f * z * z + 0.2850342711212634f;   // -(log(0.3)+0.5*log(2*pi))
    #pragma unroll
    for (int off = 32; off; off >>= 1) s += __shfl_xor(s, off, 64);
    __shared__ float wsum[4];
    if ((threadIdx.x & 63) == 0) wsum[threadIdx.x >> 6] = s;
    __syncthreads();
    if (threadIdx.x == 0)
        atomicAdd(&out[idx >= NROWS ? 1 : 0], wsum[0] + wsum[1] + wsum[2] + wsum[3]);
}

extern "C" void kernel_launch(void* const* d_in, const int* in_sizes, int n_in,
                              void* d_out, int out_size, void* d_ws, size_t ws_size,
                              hipStream_t stream) {
    const float* ex = (const float*)d_in[0];
    const float* ey = (const float*)d_in[1];
    float* out = (float*)d_out;

    char* ws = (char*)d_ws;
    unsigned char* Aq = (unsigned char*)ws;                                   // 8 MB
    unsigned char* Bq = (unsigned char*)(ws + (size_t)NROWS * D_DIM);         // 8 MB
    int* rowmax = (int*)(ws + (size_t)2 * NROWS * D_DIM);                     // 32 KB
    int* colmax = rowmax + NROWS;                                             // 32 KB

    normalize_rows<<<(2 * NROWS) / 4, 256, 0, stream>>>(ex, ey, Aq, Bq, rowmax, out);
    gemm_max<<<64 * 64, 256, 0, stream>>>(Aq, Bq, rowmax, colmax);
    finalize<<<64, 256, 0, stream>>>(rowmax, out);
}